// Round 4
// baseline (249.980 us; speedup 1.0000x reference)
//
#include <hip/hip_runtime.h>
#include <math.h>

// Quadrotor dynamics, B=2^20 independent 32-float AoS rows.
// R1: coalesced LDS staging (kernel ~88 us).
// R2: RK4 accumulator + 7-state integration -> VGPR 52, ~85.7 us.
// R3: XOR-swizzled LDS, 5 blk/CU: conflicts -80%, but swizzled GLOBAL
//     stores => +34% WRITE_SIZE. Lesson: global addrs stay lane-linear.
// R4: barrier-free wave-private regions, write-amp fixed, dur FLAT at
//     ~88 us. Occupancy ~10 waves/CU regardless of blocks/CU =>
//     NOT barrier-convoying. Diagnosis: each wave's load latency is
//     exposed serially (issue -> vmcnt(0) -> compute) and ~10 waves of
//     TLP can't cover it. VALU 19us + HBM 33us pipes both far idle.
// R5 (this): persistent waves + per-wave DOUBLE-BUFFERED software
//     pipeline (T14 issue-early / T3+T4 counted vmcnt, depth 1):
//     grid=512 (2 blocks/CU), each block loops 8 tiles of 256 rows;
//     per iteration: issue tile t+1's 9 loads FIRST, s_waitcnt vmcnt(9)
//     (waits tile t's loads only, never the new 9), compute tile t,
//     store. Load latency hides under the previous tile's compute.
//     LDS = 4 waves x 2 x 8KB = 64KB static; swizzle unchanged from R4.

#define INV_MASSF  (1.0f / 1.5f)
#define GRAVF      9.81f
#define KDF        0.1f
#define KHF        0.01f
#define JXF        0.0211f
#define JYF        0.0219f
#define JZF        0.0366f
#define JIXF       (1.0f / 0.0211f)
#define JIYF       (1.0f / 0.0219f)
#define JIZF       (1.0f / 0.0366f)
#define PI_2F      1.57079632679489661923f

#define ROWS    256          // threads per block (4 waves)
#define GRID_T  512          // target persistent grid (2 blocks/CU)

__device__ __forceinline__ float clamp1(float x) {
    return fminf(fmaxf(x, -1.0f), 1.0f);
}

// derivative of the coupled 7-state block: x = {qw,qx,qy,qz, p,q,r}
__device__ __forceinline__ void qw_deriv(const float x[7],
                                         float mx, float my, float mz,
                                         float k[7]) {
    const float ew = x[0], ex = x[1], ey = x[2], ez = x[3];
    const float p = x[4], q = x[5], r = x[6];
    k[0] = 0.5f * (-ex * p - ey * q - ez * r);
    k[1] = 0.5f * ( ew * p + ey * r - ez * q);
    k[2] = 0.5f * ( ew * q - ex * r + ez * p);
    k[3] = 0.5f * ( ew * r + ex * q - ey * p);
    const float Jwx = JXF * p, Jwy = JYF * q, Jwz = JZF * r;
    k[4] = (mx - (q * Jwz - r * Jwy)) * JIXF;
    k[5] = (my - (r * Jwx - p * Jwz)) * JIYF;
    k[6] = (mz - (p * Jwy - q * Jwx)) * JIZF;
}

// full per-row physics: logical s[32] in, logical o[32] out
__device__ __forceinline__ void qd_compute(const float s[32], float4 dl,
                                           float4 g0, float4 g1,
                                           float4 g2, float4 g3,
                                           float dt, float o[32]) {
    // ---- motor mixing: tt = G1 @ clip(delta)^2 ----
    float d0 = fminf(fmaxf(dl.x, 0.0f), 1000.0f);
    float d1 = fminf(fmaxf(dl.y, 0.0f), 1000.0f);
    float d2 = fminf(fmaxf(dl.z, 0.0f), 1000.0f);
    float d3 = fminf(fmaxf(dl.w, 0.0f), 1000.0f);
    d0 *= d0; d1 *= d1; d2 *= d2; d3 *= d3;
    const float T  = g0.x * d0 + g0.y * d1 + g0.z * d2 + g0.w * d3;
    const float Mx = g1.x * d0 + g1.y * d1 + g1.z * d2 + g1.w * d3;
    const float My = g2.x * d0 + g2.y * d1 + g2.z * d2 + g2.w * d3;
    const float Mz = g3.x * d0 + g3.y * d1 + g3.z * d2 + g3.w * d3;

    const float ew = s[9], ex = s[10], ey = s[11], ez = s[12];

    // rotation matrix from ORIGINAL quaternion
    const float r00 = ew*ew + ex*ex - ey*ey - ez*ez;
    const float r01 = 2.0f * (ex*ey - ew*ez);
    const float r02 = 2.0f * (ex*ez + ew*ey);
    const float r10 = 2.0f * (ex*ey + ew*ez);
    const float r11 = ew*ew - ex*ex + ey*ey - ez*ez;
    const float r12 = 2.0f * (ey*ez - ew*ex);
    const float r20 = 2.0f * (ex*ez - ew*ey);
    const float r21 = 2.0f * (ey*ez + ew*ex);
    const float r22 = ew*ew - ex*ex - ey*ey + ez*ez;

    // wind in body frame: R^T @ wind
    const float vwb0 = r00 * s[28] + r10 * s[29] + r20 * s[30];
    const float vwb1 = r01 * s[28] + r11 * s[29] + r21 * s[30];
    const float vwb2 = r02 * s[28] + r12 * s[29] + r22 * s[30];

    const float u_r = s[16] - vwb0;
    const float v_r = s[17] - vwb1;
    const float w_r = s[18] - vwb2;
    const float Va = sqrtf(u_r * u_r + v_r * v_r + w_r * w_r);
    const float alpha = (u_r == 0.0f) ? PI_2F : atan2f(w_r, u_r);
    const float beta  = (Va == 0.0f) ? 0.0f : asinf(clamp1(v_r / Va));

    // body forces -> inertial; v_dot is constant across all RK4 stages
    const float fx = -KDF * u_r;
    const float fy = -KDF * v_r;
    const float fz = -T - KDF * w_r + KHF * (u_r * u_r + v_r * v_r);
    const float vd0 = (r00 * fx + r01 * fy + r02 * fz) * INV_MASSF;
    const float vd1 = (r10 * fx + r11 * fy + r12 * fz) * INV_MASSF;
    const float vd2 = (r20 * fx + r21 * fy + r22 * fz) * INV_MASSF + GRAVF;

    // exact RK4 closed forms for pos/v (v_dot stage-constant)
    const float vn0 = s[13] + dt * vd0;
    const float vn1 = s[14] + dt * vd1;
    const float vn2 = s[15] + dt * vd2;
    const float hdt2 = 0.5f * dt * dt;
    const float pn0 = s[3] + dt * s[13] + hdt2 * vd0;
    const float pn1 = s[4] + dt * s[14] + hdt2 * vd1;
    const float pn2 = s[5] + dt * s[15] + hdt2 * vd2;

    // ---- RK4 on the coupled 7 states (accumulator form) ----
    const float h2 = 0.5f * dt;
    float x0[7] = {ew, ex, ey, ez, s[19], s[20], s[21]};
    float k[7], acc[7], xt[7], xn[7];
    qw_deriv(x0, Mx, My, Mz, k);
    #pragma unroll
    for (int i = 0; i < 7; ++i) { acc[i] = k[i]; xt[i] = x0[i] + h2 * k[i]; }
    qw_deriv(xt, Mx, My, Mz, k);
    #pragma unroll
    for (int i = 0; i < 7; ++i) { acc[i] += 2.0f * k[i]; xt[i] = x0[i] + h2 * k[i]; }
    qw_deriv(xt, Mx, My, Mz, k);
    #pragma unroll
    for (int i = 0; i < 7; ++i) { acc[i] += 2.0f * k[i]; xt[i] = x0[i] + dt * k[i]; }
    qw_deriv(xt, Mx, My, Mz, k);
    const float dt6 = dt / 6.0f;
    #pragma unroll
    for (int i = 0; i < 7; ++i) xn[i] = x0[i] + dt6 * (acc[i] + k[i]);

    // ---- normalize new quaternion ----
    float qw2 = xn[0], qx2 = xn[1], qy2 = xn[2], qz2 = xn[3];
    const float qi = 1.0f / sqrtf(qw2*qw2 + qx2*qx2 + qy2*qy2 + qz2*qz2);
    qw2 *= qi; qx2 *= qi; qy2 *= qi; qz2 *= qi;

    // ---- euler angles from NEW quaternion ----
    const float phi = atan2f(2.0f * (qw2 * qx2 + qy2 * qz2),
                             qw2*qw2 + qz2*qz2 - qx2*qx2 - qy2*qy2);
    const float theta = asinf(clamp1(2.0f * (qw2 * qy2 - qx2 * qz2)));
    const float psi = atan2f(2.0f * (qw2 * qz2 + qx2 * qy2),
                             qw2*qw2 + qx2*qx2 - qy2*qy2 - qz2*qz2);

    // ---- ground speed from ORIGINAL R and body velocity ----
    const float p0 = r00 * s[16] + r01 * s[17] + r02 * s[18];
    const float p1 = r10 * s[16] + r11 * s[17] + r12 * s[18];
    const float p2 = r20 * s[16] + r21 * s[17] + r22 * s[18];
    const float Vg = sqrtf(p0 * p0 + p1 * p1 + p2 * p2);
    const float vgs = (Vg == 0.0f) ? 1.0f : Vg;
    const float gamma = asinf(clamp1(p2 / vgs));
    const float chi = atan2f(p1, p0);

    // ---- assemble output row ----
    o[0] = s[0]; o[1] = s[1]; o[2] = s[2];
    o[3] = pn0; o[4] = pn1; o[5] = pn2;
    o[6] = phi; o[7] = theta; o[8] = psi;
    o[9] = qw2; o[10] = qx2; o[11] = qy2; o[12] = qz2;
    o[13] = vn0; o[14] = vn1; o[15] = vn2;
    o[16] = s[16]; o[17] = s[17]; o[18] = s[18];
    o[19] = xn[4]; o[20] = xn[5]; o[21] = xn[6];
    o[22] = Va; o[23] = Vg;
    o[24] = alpha; o[25] = beta;
    o[26] = gamma; o[27] = chi;
    o[28] = s[28]; o[29] = s[29]; o[30] = s[30]; o[31] = s[31];
}

// issue the 8 async DMAs for one wave-tile (64 rows x 128B) into buf.
// Linear LDS dest, row-permuted global source (swizzle lives on LDS side).
__device__ __forceinline__ void stage_tile(const float* __restrict__ state,
                                           int tile, int wv, int lane,
                                           float* buf) {
    const float* gb = state + ((size_t)tile * 256 + (size_t)wv * 64) * 32;
    #pragma unroll
    for (int i = 0; i < 8; ++i) {
        const int slot = i * 64 + lane;
        const int r  = slot >> 3;
        const int c4 = slot & 7;
        const int sc = c4 ^ (r & 7);
        __builtin_amdgcn_global_load_lds(
            (const __attribute__((address_space(1))) void*)
                (gb + (size_t)r * 32 + sc * 4),
            (__attribute__((address_space(3))) void*)(buf + i * 256),
            16, 0, 0);
    }
}

__global__ __launch_bounds__(ROWS, 2) void qd_dynamics_kernel(
    const float* __restrict__ state,
    const float* __restrict__ delta,
    const float* __restrict__ G1,
    const float* __restrict__ dtp,
    float* __restrict__ out,
    int B)
{
    // 4 waves x 2 buffers x 8KB = 64KB static (2 blocks/CU = 8 waves).
    __shared__ __align__(16) float lds[ROWS * 64];

    const int tid  = threadIdx.x;
    const int lane = tid & 63;
    const int wv   = tid >> 6;
    float* lw = &lds[wv * 4096];              // this wave's 2x2048f region

    const int ntiles = B >> 8;                // full 256-row tiles
    const int stride = (int)gridDim.x;
    const float dt = dtp[0];

    const float4* g4 = (const float4*)G1;     // hoisted loop-invariant loads
    const float4 g0 = g4[0], g1 = g4[1], g2 = g4[2], g3 = g4[3];

    float4 dl_cur = make_float4(0.f, 0.f, 0.f, 0.f);
    float4 dl_next = dl_cur;

    const int t0 = (int)blockIdx.x;
    if (t0 < ntiles) {
        stage_tile(state, t0, wv, lane, lw);
        dl_cur = ((const float4*)delta)[t0 * 256 + wv * 64 + lane];
    }

    int phase = 0;
    for (int t = t0; t < ntiles; t += stride) {
        float* bc = lw + (phase << 11);       // current tile's buffer
        float* bn = lw + ((phase ^ 1) << 11); // next tile's buffer
        const int tn = t + stride;

        if (tn < ntiles) {
            // issue next tile's 9 loads, then wait for everything OLDER
            // (tile t's 9 loads + previous stores) -- never the new 9.
            stage_tile(state, tn, wv, lane, bn);
            dl_next = ((const float4*)delta)[tn * 256 + wv * 64 + lane];
            asm volatile("s_waitcnt vmcnt(9)" ::: "memory");
        } else {
            asm volatile("s_waitcnt vmcnt(0)" ::: "memory");
        }

        // ---- own-row read, swizzled: physical slot lc^(lane&7) holds lc
        float s[32], o[32];
        #pragma unroll
        for (int lc = 0; lc < 8; ++lc)
            ((float4*)s)[lc] =
                *(const float4*)&bc[(lane * 8 + (lc ^ (lane & 7))) * 4];

        qd_compute(s, dl_cur, g0, g1, g2, g3, dt, o);

        // ---- own-row write (same swizzled addrs), then stage-out:
        // swizzled LDS read -> LANE-LINEAR global store (no write amp)
        #pragma unroll
        for (int lc = 0; lc < 8; ++lc)
            *(float4*)&bc[(lane * 8 + (lc ^ (lane & 7))) * 4] =
                ((const float4*)o)[lc];
        float4* ob = (float4*)(out + ((size_t)t * 256 + (size_t)wv * 64) * 32);
        #pragma unroll
        for (int i = 0; i < 8; ++i) {
            const int slot = i * 64 + lane;
            const int r  = slot >> 3;
            const int c4 = slot & 7;
            const int p  = r * 8 + (c4 ^ (r & 7));
            ob[slot] = *(const float4*)&bc[p * 4];
        }

        dl_cur = dl_next;
        phase ^= 1;
        // pin issue order: stores must not sink below next iter's DMAs,
        // else the vmcnt(9) count is wrong (slow, not incorrect).
        __builtin_amdgcn_sched_barrier(0);
    }

    // ---- remainder rows (B & 255): one block handles them directly ----
    const int rem0 = ntiles << 8;
    if (rem0 < B && (int)blockIdx.x == (ntiles % stride)) {
        const int b = rem0 + tid;
        if (b < B) {
            float s[32], o[32];
            const float4* sp = (const float4*)(state + (size_t)b * 32);
            #pragma unroll
            for (int i = 0; i < 8; ++i) ((float4*)s)[i] = sp[i];
            const float4 dl = ((const float4*)delta)[b];
            qd_compute(s, dl, g0, g1, g2, g3, dt, o);
            float4* op = (float4*)(out + (size_t)b * 32);
            #pragma unroll
            for (int i = 0; i < 8; ++i) op[i] = ((const float4*)o)[i];
        }
    }
}

extern "C" void kernel_launch(void* const* d_in, const int* in_sizes, int n_in,
                              void* d_out, int out_size, void* d_ws, size_t ws_size,
                              hipStream_t stream) {
    const float* state = (const float*)d_in[0];
    const float* delta = (const float*)d_in[1];
    const float* G1    = (const float*)d_in[2];
    const float* dtp   = (const float*)d_in[3];
    float* out = (float*)d_out;
    const int B = in_sizes[0] / 32;
    const int ntiles = B >> 8;
    int grid = (ntiles < GRID_T) ? (ntiles > 0 ? ntiles : 1) : GRID_T;
    hipLaunchKernelGGL(qd_dynamics_kernel, dim3(grid), dim3(ROWS), 0, stream,
                       state, delta, G1, dtp, out, B);
}